// Round 11
// baseline (802.418 us; speedup 1.0000x reference)
//
#include <hip/hip_runtime.h>
#include <hip/hip_cooperative_groups.h>
#include <hip/hip_fp16.h>
#include <math.h>

namespace cg = cooperative_groups;

// Problem constants
#define V    20000
#define SCV  4000
#define LL   15
#define OUTN (16384 * 128)   // B*S*D

#define LEAF_BIT 0x40000000
#define REF_MASK 0x3FFFFFFF
#define DUMMY_SLOT 89999     // total internal nodes < 90000

// ---- workspace layout (bytes) ----
#define OFF_COUNTS 0
#define OFF_ROOT   128
#define OFF_LISTS  80384
#define OFF_LEAFC  3920384
#define OFF_LEAFHH 5968384
#define OFF_EMBB   6992384
#define OFF_WT     12112384
#define OFF_CINT   12440064
#define OFF_HH     58520064

// per-height lists: h1@0 (cap 80000), h2@80000 (40000), h3@120000 (40000),
// h4@160000, h5@180000, h6@200000, h7@220000 (20000 each)
__device__ __constant__ int d_listOff[8] = {0, 0, 80000, 120000, 160000, 180000, 200000, 220000};

typedef _Float16 f16x8 __attribute__((ext_vector_type(8)));
typedef float    f32x4 __attribute__((ext_vector_type(4)));

__device__ __forceinline__ float sigm(float x) { return 1.0f / (1.0f + expf(-x)); }

// ---------------- prep: leaf h/c + embB (= emb + biases, fp16) + WT transpose ----------------
__global__ void prep_kernel(const float* __restrict__ emb,
                            const float* __restrict__ Wl, const float* __restrict__ Wlb,
                            const float* __restrict__ Wr, const float* __restrict__ Wrb,
                            float* __restrict__ leafC, __half* __restrict__ leafHh,
                            __half* __restrict__ embB, __half* __restrict__ WT) {
    int b = blockIdx.x, t = threadIdx.x;
    if (b < 2000) {                         // leaf states: 2 rows per block
        int row = b * 2 + (t >> 7);
        int i = t & 127;
        const float* e = emb + row * 640;
        float c = sigm(e[i]) * tanhf(e[512 + i]);
        float h = sigm(e[384 + i]) * tanhf(c);
        leafC[row * 128 + i] = c;
        leafHh[row * 128 + i] = __float2half(h);
    } else if (b < 4560) {                  // embB: 2,560,000 halves
        for (int i = (b - 2000) * 256 + t; i < 2560000; i += 2560 * 256) {
            int col = i % 640;
            embB[i] = __float2half(emb[i] + Wlb[col] + Wrb[col]);
        }
    } else {                                // WT[n][k] = fp16([Wl;Wr]^T), 640*256
        for (int i = (b - 4560) * 256 + t; i < 163840; i += 64 * 256) {
            int n = i >> 8, k = i & 255;
            float w = (k < 128) ? Wl[k * 640 + n] : Wr[(k - 128) * 640 + n];
            WT[i] = __float2half(w);
        }
    }
}

// ---------------- metadata: heights, compact slots, per-height lists ----------------
#define MT 128
__global__ void meta_kernel(const int* __restrict__ node_ids,
                            const int* __restrict__ left,
                            const int* __restrict__ right,
                            const int* __restrict__ last,
                            int* __restrict__ counts,
                            int* __restrict__ rootSlot,
                            int4* __restrict__ lists) {
    __shared__ int  sHei[MT][17];
    __shared__ int  sRef[MT][17];
    __shared__ int4 ebuf[MT][7];
    __shared__ int  ebin[MT][7];
    __shared__ int  locCnt[8];
    __shared__ int  basePos[8];
    __shared__ int  scanBuf[MT];
    __shared__ int  blockBase;

    int tid = threadIdx.x;
    if (tid < 8) locCnt[tid] = 0;
    __syncthreads();

    int v = blockIdx.x * MT + tid;
    int nInt = 0;
    if (v < V) {
        int l15[LL], r15[LL], id15[LL];
#pragma unroll
        for (int j = 0; j < LL; ++j) {
            l15[j]  = left[v * LL + j];
            r15[j]  = right[v * LL + j];
            id15[j] = node_ids[v * LL + j];
        }
        int lastv = last[v];
#pragma unroll
        for (int j = 0; j < LL; ++j) {
            if (j <= lastv) {
                int l = l15[j];
                if (l < 0) {
                    sHei[tid][j] = 0;
                    sRef[tid][j] = LEAF_BIT | id15[j];
                } else {
                    int r = r15[j];
                    int hl = sHei[tid][l], hr = sHei[tid][r];
                    int hh = 1 + (hl > hr ? hl : hr);
                    sHei[tid][j] = hh;
                    int pos = atomicAdd(&locCnt[hh], 1);
                    ebuf[tid][nInt] = make_int4(nInt, id15[j], sRef[tid][l], sRef[tid][r]);
                    ebin[tid][nInt] = (hh << 16) | pos;
                    sRef[tid][j] = nInt;    // local slot index (no LEAF_BIT)
                    ++nInt;
                }
            }
        }
    }
    // block-level inclusive scan of nInt -> compact slot bases
    scanBuf[tid] = nInt;
    __syncthreads();
    for (int d = 1; d < MT; d <<= 1) {
        int val = (tid >= d) ? scanBuf[tid - d] : 0;
        __syncthreads();
        scanBuf[tid] += val;
        __syncthreads();
    }
    if (tid == 0) blockBase = atomicAdd(&counts[31], scanBuf[MT - 1]);
    if (tid < 8) {
        int c = locCnt[tid];
        basePos[tid] = c ? atomicAdd(&counts[tid], c) : 0;
    }
    __syncthreads();
    int treeBase = blockBase + scanBuf[tid] - nInt;
    if (v < V) rootSlot[v] = treeBase + nInt - 1;
    for (int e = 0; e < nInt; ++e) {
        int4 E  = ebuf[tid][e];
        int md  = ebin[tid][e];
        int hh  = md >> 16, pos = md & 0xFFFF;
        E.x += treeBase;
        E.z = (E.z & LEAF_BIT) ? E.z : (E.z + treeBase);   // keep leaf tag
        E.w = (E.w & LEAF_BIT) ? E.w : (E.w + treeBase);
        lists[d_listOff[hh] + basePos[hh] + pos] = E;
    }
}

// ---------------- r8 per-chunk engine (shared by coop + fallback) ----------------
__device__ __forceinline__ void do_chunk(const int4* __restrict__ list, int cnt, int chunk,
                                         const __half* __restrict__ embB,
                                         const __half* __restrict__ WT,
                                         const __half* __restrict__ leafHh,
                                         const float* __restrict__ leafC,
                                         float* __restrict__ cInt, __half* __restrict__ hH,
                                         __half (*Ah)[264], __half (*Eb)[644], int4* meta) {
    int t = threadIdx.x;
    int lane = t & 63, wave = t >> 6;
    int ln15 = lane & 15, quad = lane >> 4;
    int base = chunk * 16;
    int rows = cnt - base; if (rows > 16) rows = 16;
    if (t < 16) {
        int4 E;
        if (t < rows) E = list[base + t];
        else { E.x = DUMMY_SLOT; E.y = 0; E.z = LEAF_BIT; E.w = LEAF_BIT; }
        meta[t] = E;
    }
    __syncthreads();
    // stage A rows: [hl fp16 (k 0..127) | hr fp16 (k 128..255)]
    for (int idx = t; idx < 512; idx += 256) {
        int m = idx >> 5, q = idx & 31;
        int ref = (q < 16) ? meta[m].z : meta[m].w;
        const __half* hs = (ref & LEAF_BIT) ? leafHh : hH;
        uint4 v = *(const uint4*)(hs + (ref & REF_MASK) * 128 + (q & 15) * 8);
        *(uint4*)(&Ah[m][q * 8]) = v;
    }
    // stage embB rows (coalesced 8B) -- consumed only in epilogue
    for (int idx = t; idx < 2560; idx += 256) {
        int m = idx / 160, q = idx - m * 160;
        uint2 v = *(const uint2*)(embB + meta[m].y * 640 + q * 4);
        *(uint2*)(&Eb[m][q * 4]) = v;
    }
    // prefetch children c (consumed only in epilogue)
    float clv[2][4], crv[2][4];
#pragma unroll
    for (int g = 0; g < 2; ++g) {
        int d = (wave + 4 * g) * 16 + ln15;
#pragma unroll
        for (int r = 0; r < 4; ++r) {
            int4 E = meta[quad * 4 + r];
            clv[g][r] = ((E.z & LEAF_BIT) ? leafC : cInt)[(E.z & REF_MASK) * 128 + d];
            crv[g][r] = ((E.w & LEAF_BIT) ? leafC : cInt)[(E.w & REF_MASK) * 128 + d];
        }
    }
    f32x4 acc[10];
#pragma unroll
    for (int p = 0; p < 10; ++p) acc[p] = (f32x4){0.f, 0.f, 0.f, 0.f};
    __syncthreads();
    // K loop: 8 steps of 32; A from LDS, B from L1/L2-resident WT
#pragma unroll 1
    for (int kb = 0; kb < 8; ++kb) {
        f16x8 af = *(const f16x8*)((const void*)&Ah[ln15][kb * 32 + quad * 8]);
#pragma unroll
        for (int p = 0; p < 10; ++p) {
            const __half* bp = WT + ((wave + 4 * p) * 16 + ln15) * 256 + kb * 32 + quad * 8;
            f16x8 bf = *(const f16x8*)((const void*)bp);
            acc[p] = __builtin_amdgcn_mfma_f32_16x16x32_f16(af, bf, acc[p], 0, 0, 0);
        }
    }
    // in-register LSTM epilogue: gate g5 of dim-group g at acc[2*g5+g]
#pragma unroll
    for (int g = 0; g < 2; ++g) {
        int d = (wave + 4 * g) * 16 + ln15;
#pragma unroll
        for (int r = 0; r < 4; ++r) {
            int m = quad * 4 + r;
            int dst = meta[m].x;
            float ig  = acc[g][r]     + __half2float(Eb[m][d]);
            float lfg = acc[2 + g][r] + __half2float(Eb[m][128 + d]);
            float rfg = acc[4 + g][r] + __half2float(Eb[m][256 + d]);
            float og  = acc[6 + g][r] + __half2float(Eb[m][384 + d]);
            float ug  = acc[8 + g][r] + __half2float(Eb[m][512 + d]);
            float c = sigm(ig) * tanhf(ug) + sigm(lfg) * clv[g][r] + sigm(rfg) * crv[g][r];
            float h2 = sigm(og) * tanhf(c);
            cInt[dst * 128 + d] = c;
            hH[dst * 128 + d] = __float2half(h2);
        }
    }
    __syncthreads();   // protect meta/Ah/Eb before next chunk
}

// ---------------- cooperative: ALL height rounds in one kernel ----------------
__launch_bounds__(256)
__global__ void round_all(const int4* __restrict__ lists, const int* __restrict__ counts,
                          const __half* __restrict__ embB, const __half* __restrict__ WT,
                          const __half* __restrict__ leafHh, const float* __restrict__ leafC,
                          float* __restrict__ cInt, __half* __restrict__ hH) {
    cg::grid_group grid = cg::this_grid();
    __shared__ __half Ah[16][264];
    __shared__ __half Eb[16][644];
    __shared__ int4 meta[16];
    for (int h = 1; h <= 7; ++h) {
        int cnt = counts[h];
        const int4* list = lists + d_listOff[h];
        int nChunks = (cnt + 15) >> 4;
        for (int chunk = blockIdx.x; chunk < nChunks; chunk += gridDim.x)
            do_chunk(list, cnt, chunk, embB, WT, leafHh, leafC, cInt, hH, Ah, Eb, meta);
        grid.sync();
    }
}

// ---------------- fallback: one height per dispatch (r8 path) ----------------
__launch_bounds__(256)
__global__ void round_one(const int4* __restrict__ list, const int* __restrict__ cntPtr,
                          const __half* __restrict__ embB, const __half* __restrict__ WT,
                          const __half* __restrict__ leafHh, const float* __restrict__ leafC,
                          float* __restrict__ cInt, __half* __restrict__ hH) {
    __shared__ __half Ah[16][264];
    __shared__ __half Eb[16][644];
    __shared__ int4 meta[16];
    int cnt = *cntPtr;
    int nChunks = (cnt + 15) >> 4;
    for (int chunk = blockIdx.x; chunk < nChunks; chunk += gridDim.x)
        do_chunk(list, cnt, chunk, embB, WT, leafHh, leafC, cInt, hH, Ah, Eb, meta);
}

// ---------------- final gather: out[b,s,:] = fp32(hH[root(input[b,s])]) ----------------
__global__ void gather_kernel(const int* __restrict__ input,
                              const int* __restrict__ rootSlot,
                              const __half* __restrict__ hH,
                              float4* __restrict__ out) {
    int idx = blockIdx.x * 256 + threadIdx.x;   // < OUTN/4
    int token = input[idx >> 5];
    int d = idx & 31;
    uint2 v = ((const uint2*)hH)[rootSlot[token] * 32 + d];
    float2 fa = __half22float2(*(__half2*)&v.x);
    float2 fb = __half22float2(*(__half2*)&v.y);
    out[idx] = make_float4(fa.x, fa.y, fb.x, fb.y);
}

extern "C" void kernel_launch(void* const* d_in, const int* in_sizes, int n_in,
                              void* d_out, int out_size, void* d_ws, size_t ws_size,
                              hipStream_t stream) {
    const int*   input    = (const int*)d_in[0];
    const int*   node_ids = (const int*)d_in[1];
    const int*   left     = (const int*)d_in[2];
    const int*   right    = (const int*)d_in[3];
    const int*   last     = (const int*)d_in[4];
    const float* emb      = (const float*)d_in[5];
    const float* Wl       = (const float*)d_in[6];
    const float* Wlb      = (const float*)d_in[7];
    const float* Wr       = (const float*)d_in[8];
    const float* Wrb      = (const float*)d_in[9];
    float* out = (float*)d_out;

    char* ws = (char*)d_ws;
    int*    counts   = (int*)(ws + OFF_COUNTS);
    int*    rootSlot = (int*)(ws + OFF_ROOT);
    int4*   lists    = (int4*)(ws + OFF_LISTS);
    float*  leafC    = (float*)(ws + OFF_LEAFC);
    __half* leafHh   = (__half*)(ws + OFF_LEAFHH);
    __half* embB     = (__half*)(ws + OFF_EMBB);
    __half* WT       = (__half*)(ws + OFF_WT);
    float*  cInt     = (float*)(ws + OFF_CINT);
    __half* hH       = (__half*)(ws + OFF_HH);

    (void)hipMemsetAsync(counts, 0, 128, stream);

    prep_kernel<<<4624, 256, 0, stream>>>(emb, Wl, Wlb, Wr, Wrb, leafC, leafHh, embB, WT);
    meta_kernel<<<(V + MT - 1) / MT, MT, 0, stream>>>(node_ids, left, right, last,
                                                      counts, rootSlot, lists);

    // size the cooperative grid from the runtime's own occupancy calc (host-only,
    // deterministic -> identical GPU work every call; cached after first call)
    static int coopBlocks = -2;   // -2 = not yet queried
    if (coopBlocks == -2) {
        int perCU = 0, numCU = 0;
        hipError_t e1 = hipOccupancyMaxActiveBlocksPerMultiprocessor(&perCU, round_all, 256, 0);
        hipError_t e2 = hipDeviceGetAttribute(&numCU, hipDeviceAttributeMultiprocessorCount, 0);
        coopBlocks = (e1 == hipSuccess && e2 == hipSuccess && perCU > 0) ? perCU * numCU : -1;
        if (coopBlocks > 1920) coopBlocks = 1920;
    }

    static const int h_listOff[8] = {0, 0, 80000, 120000, 160000, 180000, 200000, 220000};
    bool coopDone = false;
    if (coopBlocks > 0) {
        void* args[] = { (void*)&lists, (void*)&counts, (void*)&embB, (void*)&WT,
                         (void*)&leafHh, (void*)&leafC, (void*)&cInt, (void*)&hH };
        hipError_t ce = hipLaunchCooperativeKernel(round_all, dim3(coopBlocks), dim3(256),
                                                   args, 0, stream);
        coopDone = (ce == hipSuccess);
    }
    if (!coopDone) {
        for (int h = 1; h <= 7; ++h) {
            round_one<<<1920, 256, 0, stream>>>(
                lists + h_listOff[h], counts + h,
                embB, WT, leafHh, leafC, cInt, hH);
        }
    }

    gather_kernel<<<OUTN / 4 / 256, 256, 0, stream>>>(input, rootSlot, hH, (float4*)out);
}

// Round 12
// 452.989 us; speedup vs baseline: 1.7714x; 1.7714x over previous
//
#include <hip/hip_runtime.h>
#include <hip/hip_fp16.h>
#include <math.h>

// Problem constants
#define V    20000
#define SCV  4000
#define LL   15
#define OUTN (16384 * 128)   // B*S*D

#define LEAF_BIT 0x40000000
#define REF_MASK 0x3FFFFFFF

// ---- workspace layout (bytes) ----
// counts int[32] @0
// trees: 7 bins x 20000 trees x 8 int4 (128B/tree) @128   (17.92 MB)
// leafC f32[4000*128] @17920128 ; leafHh fp16 @19968128 ; embB fp16[4000*640] @20992128
// WT fp16[640*256] @26112128 ; hRoot fp16[20000*128] @26439808  (ends ~31.6 MB)
#define OFF_COUNTS 0
#define OFF_TREES  128
#define OFF_LEAFC  17920128
#define OFF_LEAFHH 19968128
#define OFF_EMBB   20992128
#define OFF_WT     26112128
#define OFF_HROOT  26439808

#define TPB 12            // trees per block
#define TREE_BLOCKS 1664

typedef _Float16 f16x8 __attribute__((ext_vector_type(8)));
typedef float    f32x4 __attribute__((ext_vector_type(4)));

__device__ __forceinline__ float sigm(float x) { return 1.0f / (1.0f + expf(-x)); }

// ---------------- prep: leaf h/c + embB (= emb + biases, fp16) + WT transpose ----------------
__global__ void prep_kernel(const float* __restrict__ emb,
                            const float* __restrict__ Wl, const float* __restrict__ Wlb,
                            const float* __restrict__ Wr, const float* __restrict__ Wrb,
                            float* __restrict__ leafC, __half* __restrict__ leafHh,
                            __half* __restrict__ embB, __half* __restrict__ WT) {
    int b = blockIdx.x, t = threadIdx.x;
    if (b < 2000) {                         // leaf states: 2 rows per block
        int row = b * 2 + (t >> 7);
        int i = t & 127;
        const float* e = emb + row * 640;
        float c = sigm(e[i]) * tanhf(e[512 + i]);
        float h = sigm(e[384 + i]) * tanhf(c);
        leafC[row * 128 + i] = c;
        leafHh[row * 128 + i] = __float2half(h);
    } else if (b < 4560) {                  // embB: 2,560,000 halves
        for (int i = (b - 2000) * 256 + t; i < 2560000; i += 2560 * 256) {
            int col = i % 640;
            embB[i] = __float2half(emb[i] + Wlb[col] + Wrb[col]);
        }
    } else {                                // WT[n][k] = fp16([Wl;Wr]^T), 640*256
        for (int i = (b - 4560) * 256 + t; i < 163840; i += 64 * 256) {
            int n = i >> 8, k = i & 255;
            float w = (k < 128) ? Wl[k * 640 + n] : Wr[(k - 128) * 640 + n];
            WT[i] = __float2half(w);
        }
    }
}

// ---------------- metadata: per-tree descriptors, binned by internal-node count ----------------
// descriptor = 8 int4: [0]=(v, nInt, 0, 0); [1+j]=(node_id, refL, refR, 0) with
// ref = LEAF_BIT|subcharId for leaf child, or LOCAL internal index (0..5) otherwise.
#define MT 128
__global__ void meta_kernel(const int* __restrict__ node_ids,
                            const int* __restrict__ left,
                            const int* __restrict__ right,
                            const int* __restrict__ last,
                            int* __restrict__ counts,
                            int4* __restrict__ trees) {
    __shared__ int sRef[MT][17];
    __shared__ int locCnt[8];
    __shared__ int basePos[8];

    int tid = threadIdx.x;
    if (tid < 8) locCnt[tid] = 0;
    __syncthreads();

    int v = blockIdx.x * MT + tid;
    int nInt = 0;
    int4 desc[8];
#pragma unroll
    for (int w = 0; w < 8; ++w) desc[w] = make_int4(0, 0, 0, 0);
    if (v < V) {
        int l15[LL], r15[LL], id15[LL];
#pragma unroll
        for (int j = 0; j < LL; ++j) {
            l15[j]  = left[v * LL + j];
            r15[j]  = right[v * LL + j];
            id15[j] = node_ids[v * LL + j];
        }
        int lastv = last[v];
#pragma unroll
        for (int j = 0; j < LL; ++j) {
            if (j <= lastv) {
                int l = l15[j];
                if (l < 0) {
                    sRef[tid][j] = LEAF_BIT | id15[j];
                } else {
                    desc[1 + nInt] = make_int4(id15[j], sRef[tid][l], sRef[tid][r15[j]], 0);
                    sRef[tid][j] = nInt;    // local internal index
                    ++nInt;
                }
            }
        }
        desc[0] = make_int4(v, nInt, 0, 0);
    }
    int pos = 0;
    if (v < V) pos = atomicAdd(&locCnt[nInt], 1);
    __syncthreads();
    if (tid < 8) {
        int c = locCnt[tid];
        basePos[tid] = c ? atomicAdd(&counts[tid], c) : 0;
    }
    __syncthreads();
    if (v < V) {
        int g = basePos[nInt] + pos;
        int4* dst = trees + (size_t)(nInt - 1) * 20000 * 8 + (size_t)g * 8;
#pragma unroll
        for (int w = 0; w < 8; ++w) dst[w] = desc[w];
    }
}

// ---------------- tree kernel: whole trees in LDS, one dispatch for everything ----------------
// block = 12 trees from one bin (uniform nInt). step j = one 16-row MFMA chunk
// (rows 12-15 duplicate tree 11 -- benign). h/c of internal nodes live in LDS;
// leaves + embB + WT are L2-resident tables; only root h is written to global.
__launch_bounds__(256)
__global__ void tree_kernel(const int4* __restrict__ trees, const int* __restrict__ counts,
                            const __half* __restrict__ embB, const __half* __restrict__ WT,
                            const __half* __restrict__ leafHh, const float* __restrict__ leafC,
                            __half* __restrict__ hRoot) {
    __shared__ __half hS[TPB][6][132];   // internal-node h (slots 0..5; root h -> hRoot)
    __shared__ float  cS[TPB][6][132];   // internal-node c (slots 0..5)
    __shared__ int4   metaS[TPB * 8];

    int t = threadIdx.x;
    int lane = t & 63, wave = t >> 6;        // 4 waves
    int ln15 = lane & 15, quad = lane >> 4;
    int ln15c = ln15 < TPB ? ln15 : TPB - 1;

    // bin prefix (7 loads per block)
    int pre[8];
    pre[0] = 0;
#pragma unroll
    for (int n = 1; n <= 7; ++n) pre[n] = pre[n - 1] + (counts[n] + TPB - 1) / TPB;
    int total = pre[7];

    for (int chunk = blockIdx.x; chunk < total; chunk += gridDim.x) {
        int b = 1;
        while (chunk >= pre[b]) ++b;         // bin index = nInt
        int lc = chunk - pre[b - 1];
        const int4* binBase = trees + (size_t)(b - 1) * 20000 * 8;
        int cnt = counts[b];
        int base = lc * TPB;
        int rows = cnt - base; if (rows > TPB) rows = TPB;
        // stage descriptors (dup first tree for tail rows -> benign double writes)
        if (t < TPB * 8) {
            int m = t >> 3, w = t & 7;
            int src = base + (m < rows ? m : 0);
            metaS[t] = binBase[(size_t)src * 8 + w];
        }
        __syncthreads();
        int nInt = b;
        for (int j = 0; j < nInt; ++j) {
            // refs for this lane's A row (tree ln15c, node j)
            int4 Ea = metaS[ln15c * 8 + 1 + j];
            // epilogue metadata + register prefetch (issued before K loop)
            int4 Em[4];
#pragma unroll
            for (int r = 0; r < 4; ++r) {
                int mm = quad * 4 + r; if (mm >= TPB) mm = TPB - 1;
                Em[r] = metaS[mm * 8 + 1 + j];
            }
            __half ebv[2][4][5];
            float clv[2][4], crv[2][4];
#pragma unroll
            for (int g = 0; g < 2; ++g) {
                int d = (wave + 4 * g) * 16 + ln15;
#pragma unroll
                for (int r = 0; r < 4; ++r) {
                    const __half* ep = embB + (size_t)Em[r].x * 640 + d;
#pragma unroll
                    for (int q = 0; q < 5; ++q) ebv[g][r][q] = ep[q * 128];
                    int rl = Em[r].y, rr = Em[r].z;
                    clv[g][r] = (rl & LEAF_BIT) ? leafC[(rl & REF_MASK) * 128 + d] : 0.f;
                    crv[g][r] = (rr & LEAF_BIT) ? leafC[(rr & REF_MASK) * 128 + d] : 0.f;
                }
            }
            f32x4 acc[10];
#pragma unroll
            for (int p = 0; p < 10; ++p) acc[p] = (f32x4){0.f, 0.f, 0.f, 0.f};
            // K loop: 8 steps of 32. A row = [h_left | h_right] of tree ln15's node j,
            // read per-lane from LDS (internal child) or L2-hot leafHh (leaf child).
#pragma unroll 1
            for (int kb = 0; kb < 8; ++kb) {
                int ref = (kb < 4) ? Ea.y : Ea.z;
                f16x8 af;
                if (ref & LEAF_BIT)
                    af = *(const f16x8*)((const void*)(leafHh + (ref & REF_MASK) * 128
                                                      + (kb & 3) * 32 + quad * 8));
                else
                    af = *(const f16x8*)((const void*)&hS[ln15c][ref][(kb & 3) * 32 + quad * 8]);
#pragma unroll
                for (int p = 0; p < 10; ++p) {
                    const __half* bp = WT + ((wave + 4 * p) * 16 + ln15) * 256
                                       + kb * 32 + quad * 8;
                    f16x8 bf = *(const f16x8*)((const void*)bp);
                    acc[p] = __builtin_amdgcn_mfma_f32_16x16x32_f16(af, bf, acc[p], 0, 0, 0);
                }
            }
            // in-register LSTM epilogue: gate q of dim-group g at acc[2q+g]
#pragma unroll
            for (int g = 0; g < 2; ++g) {
                int d = (wave + 4 * g) * 16 + ln15;
#pragma unroll
                for (int r = 0; r < 4; ++r) {
                    int mm = quad * 4 + r; if (mm >= TPB) mm = TPB - 1;
                    int4 E = Em[r];
                    float ig  = acc[g][r]     + __half2float(ebv[g][r][0]);
                    float lfg = acc[2 + g][r] + __half2float(ebv[g][r][1]);
                    float rfg = acc[4 + g][r] + __half2float(ebv[g][r][2]);
                    float og  = acc[6 + g][r] + __half2float(ebv[g][r][3]);
                    float ug  = acc[8 + g][r] + __half2float(ebv[g][r][4]);
                    float cl = (E.y & LEAF_BIT) ? clv[g][r] : cS[mm][E.y][d];
                    float cr = (E.z & LEAF_BIT) ? crv[g][r] : cS[mm][E.z][d];
                    float c = sigm(ig) * tanhf(ug) + sigm(lfg) * cl + sigm(rfg) * cr;
                    float h = sigm(og) * tanhf(c);
                    if (j < nInt - 1) {
                        cS[mm][j][d] = c;
                        hS[mm][j][d] = __float2half(h);
                    } else {
                        hRoot[(size_t)metaS[mm * 8].x * 128 + d] = __float2half(h);
                    }
                }
            }
            __syncthreads();   // hS/cS of step j visible before step j+1 / next chunk staging
        }
    }
}

// ---------------- final gather: out[b,s,:] = fp32(hRoot[input[b,s]]) ----------------
__global__ void gather_kernel(const int* __restrict__ input,
                              const __half* __restrict__ hRoot,
                              float4* __restrict__ out) {
    int idx = blockIdx.x * 256 + threadIdx.x;   // < OUTN/4
    int token = input[idx >> 5];
    int d = idx & 31;
    uint2 v = ((const uint2*)hRoot)[token * 32 + d];
    float2 fa = __half22float2(*(__half2*)&v.x);
    float2 fb = __half22float2(*(__half2*)&v.y);
    out[idx] = make_float4(fa.x, fa.y, fb.x, fb.y);
}

extern "C" void kernel_launch(void* const* d_in, const int* in_sizes, int n_in,
                              void* d_out, int out_size, void* d_ws, size_t ws_size,
                              hipStream_t stream) {
    const int*   input    = (const int*)d_in[0];
    const int*   node_ids = (const int*)d_in[1];
    const int*   left     = (const int*)d_in[2];
    const int*   right    = (const int*)d_in[3];
    const int*   last     = (const int*)d_in[4];
    const float* emb      = (const float*)d_in[5];
    const float* Wl       = (const float*)d_in[6];
    const float* Wlb      = (const float*)d_in[7];
    const float* Wr       = (const float*)d_in[8];
    const float* Wrb      = (const float*)d_in[9];
    float* out = (float*)d_out;

    char* ws = (char*)d_ws;
    int*    counts   = (int*)(ws + OFF_COUNTS);
    int4*   trees    = (int4*)(ws + OFF_TREES);
    float*  leafC    = (float*)(ws + OFF_LEAFC);
    __half* leafHh   = (__half*)(ws + OFF_LEAFHH);
    __half* embB     = (__half*)(ws + OFF_EMBB);
    __half* WT       = (__half*)(ws + OFF_WT);
    __half* hRoot    = (__half*)(ws + OFF_HROOT);

    (void)hipMemsetAsync(counts, 0, 128, stream);

    prep_kernel<<<4624, 256, 0, stream>>>(emb, Wl, Wlb, Wr, Wrb, leafC, leafHh, embB, WT);
    meta_kernel<<<(V + MT - 1) / MT, MT, 0, stream>>>(node_ids, left, right, last,
                                                      counts, trees);
    tree_kernel<<<TREE_BLOCKS, 256, 0, stream>>>(trees, counts, embB, WT,
                                                 leafHh, leafC, hRoot);
    gather_kernel<<<OUTN / 4 / 256, 256, 0, stream>>>(input, hRoot, (float4*)out);
}